// Round 6
// baseline (301.900 us; speedup 1.0000x reference)
//
#include <hip/hip_runtime.h>
#include <cstdint>
#include <cstddef>

// ---------- types ----------
typedef __bf16 bf16_t;
typedef __bf16 bf16x8 __attribute__((ext_vector_type(8)));
typedef __bf16 bf16x4 __attribute__((ext_vector_type(4)));
typedef float f32x4 __attribute__((ext_vector_type(4)));

// async global->LDS, 16B per lane. LDS dest must be wave-uniform base + lane*16.
#define GL2LDS16(gptr, lptr)                                                   \
  __builtin_amdgcn_global_load_lds(                                            \
      (__attribute__((address_space(1))) void*)(gptr),                         \
      (__attribute__((address_space(3))) void*)(lptr), 16, 0, 0)

// fast 2^x (hardware transcendental; inputs bounded here)
__device__ __forceinline__ float fast_exp2(float x) {
  float r;
  asm volatile("v_exp_f32 %0, %1" : "=v"(r) : "v"(x));
  return r;
}

// ---------- problem constants ----------
#define BATCH 2
#define T_SEQ 2048
#define NH 16
#define NKV 4
#define HD 128
#define EMB 2048
#define KVDIM (NKV * HD)       // 512
#define MROWS (BATCH * T_SEQ)  // 4096

// =====================================================================
// fused fp32 -> bf16 conversion for all 5 inputs (one dispatch)
// =====================================================================
__global__ void cvt_all(const float4* __restrict__ x,  const float4* __restrict__ wq,
                        const float4* __restrict__ wk, const float4* __restrict__ wv,
                        const float4* __restrict__ wo,
                        bf16x4* __restrict__ xb,  bf16x4* __restrict__ wqb,
                        bf16x4* __restrict__ wkb, bf16x4* __restrict__ wvb,
                        bf16x4* __restrict__ wob) {
  const int blk = blockIdx.x;
  const float4* src;
  bf16x4* dst;
  int base;
  if (blk < 8192)       { src = x;  dst = xb;  base = blk; }
  else if (blk < 12288) { src = wq; dst = wqb; base = blk - 8192; }
  else if (blk < 13312) { src = wk; dst = wkb; base = blk - 12288; }
  else if (blk < 14336) { src = wv; dst = wvb; base = blk - 13312; }
  else                  { src = wo; dst = wob; base = blk - 14336; }
  const int i = base * 256 + threadIdx.x;
  const float4 v = src[i];
  dst[i] = bf16x4{(__bf16)v.x, (__bf16)v.y, (__bf16)v.z, (__bf16)v.w};
}

// =====================================================================
// Fused QKV GEMM — R2-exact 256x256 8-phase schedule (best measured:
// 67.3 µs). 8 waves, wave tile 128x64, BK=64, LDS 128 KiB, 16B-block
// XOR swizzle, counted vmcnt(6) once per K-tile, setprio around MFMA.
// Region liveness: A free after ph3, B free after ph2.
// Stage slots: ph1 -> (t+1).A1 [nxt]; ph2 -> none;
//              ph3 -> (t+2).B0 [cur]; ph4 -> (t+2).A0 + (t+2).B1 [cur].
// N tiles: [0,8) Q | [8,10) K | [10,12) V^T.  Grid: 192 blocks, XCD-swizzled.
// =====================================================================
#define BK8 64
#define NT8 (EMB / BK8)  // 32

__global__ __launch_bounds__(512, 2)
void gemm_qkv8(const bf16_t* __restrict__ A,
               const bf16_t* __restrict__ Wq, const bf16_t* __restrict__ Wk,
               const bf16_t* __restrict__ Wv,
               bf16_t* __restrict__ Qb, bf16_t* __restrict__ Kb,
               bf16_t* __restrict__ Vt, float qalpha)
{
  // rows 0..255: A tile (two 128-row halves), rows 256..511: B tile.
  __shared__ bf16_t lds[2][512 * 64];

  const int tid  = threadIdx.x;
  const int lane = tid & 63;
  const int wv   = tid >> 6;
  const int l15  = lane & 15;
  const int lq   = lane >> 4;

  // XCD-aware bijective swizzle: 192 blocks = 8 XCDs x 24.
  const int bid0 = blockIdx.x;
  const int bid  = (bid0 & 7) * 24 + (bid0 >> 3);
  const int mt = bid / 12, nt = bid % 12;
  const int m0 = mt * 256;

  const bf16_t* Bmat; int ncol0, seg;
  if (nt < 8)       { Bmat = Wq; ncol0 = nt * 256;        seg = 0; }
  else if (nt < 10) { Bmat = Wk; ncol0 = (nt - 8) * 256;  seg = 1; }
  else              { Bmat = Wv; ncol0 = (nt - 10) * 256; seg = 2; }

  const int wm = (wv >> 2) * 128;  // wave M offset (0/128)
  const int wn = (wv & 3) * 64;    // wave N offset (0/64/128/192)

  f32x4 acc[8][4] = {};

  // stage half-tile h of K-tile tsrc into lds[dbuf].
  auto stage = [&](int dbuf, int tsrc, int h) {
    const int k0 = tsrc * BK8;
    const bf16_t* src = (h < 2) ? A : Bmat;
    const int rbase = (h < 2) ? (m0 + h * 128) : (ncol0 + (h - 2) * 128);
    bf16_t* dst = &lds[dbuf][h * 8192];
#pragma unroll
    for (int r = 0; r < 2; ++r) {
      const int c = r * 512 + tid;          // 0..1023, 16B granules
      const int row = c >> 3, p = c & 7;
      const int sb = p ^ (row & 7);
      GL2LDS16(src + (size_t)(rbase + row) * EMB + k0 + sb * 8, dst + c * 8);
    }
  };

  // ---- prologue: tile0 complete + tile1 {B0,A0,B1} in flight ----
  stage(0, 0, 0); stage(0, 0, 1); stage(0, 0, 2); stage(0, 0, 3);
  stage(1, 1, 2); stage(1, 1, 0); stage(1, 1, 3);
  asm volatile("s_waitcnt vmcnt(6)" ::: "memory");  // tile0's 8 loads landed
  __builtin_amdgcn_s_barrier();

  bf16x8 a[4][2], b[4][2];

#pragma unroll 1
  for (int tt = 0; tt < NT8; tt += 2) {
#pragma unroll
    for (int u = 0; u < 2; ++u) {
      const int t   = tt + u;
      const int cur = u;
      const int nxt = u ^ 1;
      const int tn1 = (t + 1 < NT8) ? t + 1 : NT8 - 1;  // clamp src only;
      const int tn2 = (t + 2 < NT8) ? t + 2 : NT8 - 1;  // dest parity stays

      // ------- phase 1: read A[i0-3], B[j0-1]; stage (t+1).A1 [nxt] ------
#pragma unroll
      for (int i = 0; i < 4; ++i) {
        const int row = wm + i * 16 + l15;
#pragma unroll
        for (int ks = 0; ks < 2; ++ks)
          a[i][ks] = *(const bf16x8*)&lds[cur][row * 64 + (((ks * 4 + lq) ^ (row & 7)) * 8)];
      }
#pragma unroll
      for (int j = 0; j < 2; ++j) {
        const int row = 256 + wn + j * 16 + l15;
#pragma unroll
        for (int ks = 0; ks < 2; ++ks)
          b[j][ks] = *(const bf16x8*)&lds[cur][row * 64 + (((ks * 4 + lq) ^ (row & 7)) * 8)];
      }
      stage(nxt, tn1, 1);
      __builtin_amdgcn_s_barrier();
      __builtin_amdgcn_s_setprio(1);
#pragma unroll
      for (int ks = 0; ks < 2; ++ks)
#pragma unroll
        for (int i = 0; i < 4; ++i)
#pragma unroll
          for (int j = 0; j < 2; ++j)
            acc[i][j] = __builtin_amdgcn_mfma_f32_16x16x32_bf16(a[i][ks], b[j][ks], acc[i][j], 0, 0, 0);
      __builtin_amdgcn_s_setprio(0);
      __builtin_amdgcn_s_barrier();

      // ------- phase 2: read B[j2-3]; NO stage (all cur regions live) ----
#pragma unroll
      for (int j = 2; j < 4; ++j) {
        const int row = 256 + wn + j * 16 + l15;
#pragma unroll
        for (int ks = 0; ks < 2; ++ks)
          b[j][ks] = *(const bf16x8*)&lds[cur][row * 64 + (((ks * 4 + lq) ^ (row & 7)) * 8)];
      }
      __builtin_amdgcn_s_barrier();
      __builtin_amdgcn_s_setprio(1);
#pragma unroll
      for (int ks = 0; ks < 2; ++ks)
#pragma unroll
        for (int i = 0; i < 4; ++i)
#pragma unroll
          for (int j = 2; j < 4; ++j)
            acc[i][j] = __builtin_amdgcn_mfma_f32_16x16x32_bf16(a[i][ks], b[j][ks], acc[i][j], 0, 0, 0);
      __builtin_amdgcn_s_setprio(0);
      __builtin_amdgcn_s_barrier();

      // ------- phase 3: read A[i4-7]; stage (t+2).B0 (B free after ph2) --
#pragma unroll
      for (int i = 0; i < 4; ++i) {
        const int row = wm + (4 + i) * 16 + l15;
#pragma unroll
        for (int ks = 0; ks < 2; ++ks)
          a[i][ks] = *(const bf16x8*)&lds[cur][row * 64 + (((ks * 4 + lq) ^ (row & 7)) * 8)];
      }
      stage(cur, tn2, 2);
      __builtin_amdgcn_s_barrier();
      __builtin_amdgcn_s_setprio(1);
#pragma unroll
      for (int ks = 0; ks < 2; ++ks)
#pragma unroll
        for (int i = 0; i < 4; ++i)
#pragma unroll
          for (int j = 2; j < 4; ++j)
            acc[4 + i][j] = __builtin_amdgcn_mfma_f32_16x16x32_bf16(a[i][ks], b[j][ks], acc[4 + i][j], 0, 0, 0);
      __builtin_amdgcn_s_setprio(0);
      __builtin_amdgcn_s_barrier();

      // ------- phase 4: stage (t+2).A0 + (t+2).B1 (A free after ph3) -----
      stage(cur, tn2, 0);
      stage(cur, tn2, 3);
      __builtin_amdgcn_s_barrier();
      __builtin_amdgcn_s_setprio(1);
#pragma unroll
      for (int ks = 0; ks < 2; ++ks)
#pragma unroll
        for (int i = 0; i < 4; ++i)
#pragma unroll
          for (int j = 0; j < 2; ++j)
            acc[4 + i][j] = __builtin_amdgcn_mfma_f32_16x16x32_bf16(a[i][ks], b[j][ks], acc[4 + i][j], 0, 0, 0);
      __builtin_amdgcn_s_setprio(0);
      asm volatile("s_waitcnt vmcnt(6)" ::: "memory");
      __builtin_amdgcn_s_barrier();
    }
  }
  asm volatile("s_waitcnt vmcnt(0)" ::: "memory");  // drain tail dummies

  // ---- epilogue ----
  if (seg == 0) {          // Q: scale + row-major (4096,2048)
#pragma unroll
    for (int i = 0; i < 8; ++i) {
      const int rbase = m0 + wm + i * 16 + lq * 4;
#pragma unroll
      for (int j = 0; j < 4; ++j) {
        const int col = ncol0 + wn + j * 16 + l15;
#pragma unroll
        for (int r = 0; r < 4; ++r)
          Qb[(size_t)(rbase + r) * EMB + col] = (bf16_t)(acc[i][j][r] * qalpha);
      }
    }
  } else if (seg == 1) {   // K: row-major (4096,512)
#pragma unroll
    for (int i = 0; i < 8; ++i) {
      const int rbase = m0 + wm + i * 16 + lq * 4;
#pragma unroll
      for (int j = 0; j < 4; ++j) {
        const int col = ncol0 + wn + j * 16 + l15;
#pragma unroll
        for (int r = 0; r < 4; ++r)
          Kb[(size_t)(rbase + r) * KVDIM + col] = (bf16_t)acc[i][j][r];
      }
    }
  } else {                 // V: transposed, 4 consecutive t per lane
    const int bb = m0 >> 11;
    const int mloc0 = (m0 & 2047) + wm + lq * 4;
#pragma unroll
    for (int i = 0; i < 8; ++i) {
      const int mloc = mloc0 + i * 16;
#pragma unroll
      for (int j = 0; j < 4; ++j) {
        const int d = ncol0 + wn + j * 16 + l15;
        *(bf16x4*)(Vt + (size_t)(bb * KVDIM + d) * T_SEQ + mloc) =
            bf16x4{(__bf16)acc[i][j][0], (__bf16)acc[i][j][1],
                   (__bf16)acc[i][j][2], (__bf16)acc[i][j][3]};
      }
    }
  }
}

// =====================================================================
// GEMM (out-projection): fp32 out.
// =====================================================================
__global__ __launch_bounds__(256, 2)
void gemm_out(const bf16_t* __restrict__ A, const bf16_t* __restrict__ Bm,
              float* __restrict__ C, int M, int N, int K)
{
  __shared__ bf16_t As[128 * 64];
  __shared__ bf16_t Bs[128 * 64];

  const int tid  = threadIdx.x;
  const int lane = tid & 63;
  const int wv   = tid >> 6;
  const int m0 = blockIdx.y * 128;
  const int n0 = blockIdx.x * 128;
  const int wm = (wv >> 1) * 64;
  const int wn = (wv & 1) * 64;
  const int l15 = lane & 15;
  const int lq  = lane >> 4;

  f32x4 acc[4][4] = {};
  const int srow = tid >> 3;
  const int scol = (tid & 7) * 8;

  for (int k0 = 0; k0 < K; k0 += 64) {
#pragma unroll
    for (int r = 0; r < 4; ++r) {
      const int row = r * 32 + srow;
      GL2LDS16(A + (size_t)(m0 + row) * K + k0 + scol, As + row * 64 + scol);
    }
#pragma unroll
    for (int r = 0; r < 4; ++r) {
      const int row = r * 32 + srow;
      GL2LDS16(Bm + (size_t)(n0 + row) * K + k0 + scol, Bs + row * 64 + scol);
    }
    __syncthreads();

#pragma unroll
    for (int ks = 0; ks < 2; ++ks) {
      const int kc = ks * 32 + lq * 8;
      bf16x8 af[4], bf[4];
#pragma unroll
      for (int i = 0; i < 4; ++i)
        af[i] = *(const bf16x8*)(As + (wm + i * 16 + l15) * 64 + kc);
#pragma unroll
      for (int j = 0; j < 4; ++j)
        bf[j] = *(const bf16x8*)(Bs + (wn + j * 16 + l15) * 64 + kc);
#pragma unroll
      for (int i = 0; i < 4; ++i)
#pragma unroll
        for (int j = 0; j < 4; ++j)
          acc[i][j] = __builtin_amdgcn_mfma_f32_16x16x32_bf16(af[i], bf[j], acc[i][j], 0, 0, 0);
    }
    __syncthreads();
  }

#pragma unroll
  for (int i = 0; i < 4; ++i) {
    const int rbase = m0 + wm + i * 16 + lq * 4;
#pragma unroll
    for (int j = 0; j < 4; ++j) {
      const int col = n0 + wn + j * 16 + l15;
#pragma unroll
      for (int r = 0; r < 4; ++r)
        C[(size_t)(rbase + r) * N + col] = acc[i][j][r];
    }
  }
}

// =====================================================================
// Flash attention — 32 q-rows PER WAVE (two l15-fragments f=0/1).
// K/V fragment reads shared across f: MFMA per wave-iter doubles
// (32->64) at constant K/V LDS traffic -> MFMA:LDS ratio 2x, 16
// independent acc chains. Block q-tile 128 (4 waves x 32), kv tile 64,
// K/V double-buffered, no-max exp2 softmax, S^T orientation, P via
// per-wave LDS (32 rows). Grid (8,NH,B)=256 blocks = 1/CU; causal
// pairing qt=15-x then qt=x -> 34 kv-iters per block, uniform.
// Masking: only last TWO kv tiles need the elementwise kvb<=qabs test
// (tile 2qt: diagonal for lower q-half; tile 2qt+1: diagonal upper /
// fully-masked lower -> exact elementwise either way).
// LDS: Ks 32K + Vs 32K + Ps 4x32x72x2 = 84 KB -> 1 block/CU.
// =====================================================================
#define PSTR 72   // row stride (elements); 144 B = 16B-aligned

__global__ __launch_bounds__(256, 1)
void attn_fwd(const bf16_t* __restrict__ Q, const bf16_t* __restrict__ Kg,
              const bf16_t* __restrict__ Vt, bf16_t* __restrict__ Y)
{
  __shared__ bf16_t Ks[2][64 * 128];   // [t 0..63][16B blk], blk = pos ^ (t&7)
  __shared__ bf16_t Vs[2][128 * 64];   // [d 0..127][16B blk], blk = pos ^ (d&7)
  __shared__ bf16_t Ps[4][32 * PSTR];  // per-wave P[q 0..31][kv 0..63]

  const int tid  = threadIdx.x;
  const int lane = tid & 63;
  const int wv   = tid >> 6;
  const int l15  = lane & 15;
  const int lq   = lane >> 4;
  const int h  = blockIdx.y;
  const int b  = blockIdx.z;
  const int hkv = h >> 2;
  bf16_t* Psw = Ps[wv];

  auto stage = [&](int kt, int bufsel) {
    const int base_t = b * T_SEQ + kt * 64;
#pragma unroll
    for (int r = 0; r < 4; ++r) {
      const int c = r * 256 + tid;
      const int row = c >> 4, p = c & 15;
      const int sb = p ^ (row & 7);
      GL2LDS16(Kg + (size_t)(base_t + row) * KVDIM + hkv * HD + sb * 8,
               &Ks[bufsel][c * 8]);
    }
#pragma unroll
    for (int r = 0; r < 4; ++r) {
      const int c = r * 256 + tid;
      const int row = c >> 3, p = c & 7;
      const int sb = p ^ (row & 7);
      GL2LDS16(Vt + (size_t)(b * KVDIM + hkv * HD + row) * T_SEQ + kt * 64 + sb * 8,
               &Vs[bufsel][c * 8]);
    }
  };

#pragma unroll 1
  for (int ph = 0; ph < 2; ++ph) {
    const int qt = ph ? blockIdx.x : (15 - blockIdx.x);
    const int q0 = qt * 128;
    const int nkt = 2 * qt + 2;            // kv tiles of 64
    const int qa0 = q0 + wv * 32 + l15;    // f=0 q row
    const int qa1 = qa0 + 16;              // f=1 q row

    // Q fragments (B-operand: n=l15=q, k=lq*8+j). Q pre-scaled.
    bf16x8 qf0[4], qf1[4];
    {
      const bf16_t* qp0 = Q + ((size_t)(b * T_SEQ + qa0) * NH + h) * HD + lq * 8;
      const bf16_t* qp1 = Q + ((size_t)(b * T_SEQ + qa1) * NH + h) * HD + lq * 8;
#pragma unroll
      for (int ds = 0; ds < 4; ++ds) {
        qf0[ds] = *(const bf16x8*)(qp0 + ds * 32);
        qf1[ds] = *(const bf16x8*)(qp1 + ds * 32);
      }
    }

    float l0 = 0.f, l1 = 0.f;
    f32x4 o0[8], o1[8];
#pragma unroll
    for (int nb = 0; nb < 8; ++nb) {
      o0[nb] = f32x4{0.f, 0.f, 0.f, 0.f};
      o1[nb] = f32x4{0.f, 0.f, 0.f, 0.f};
    }

    __syncthreads();            // prior phase done reading buffers
    stage(0, 0);

    for (int kt = 0; kt < nkt; ++kt) {
      const int cur = kt & 1;
      __syncthreads();          // stage(kt) complete
      if (kt + 1 < nkt) stage(kt + 1, cur ^ 1);

      // ---- S^T = K Q^T : D[kv][q]. kf read ONCE, used for both f ----
      f32x4 s0[4], s1[4];
#pragma unroll
      for (int nb = 0; nb < 4; ++nb) {
        s0[nb] = f32x4{0.f, 0.f, 0.f, 0.f};
        s1[nb] = f32x4{0.f, 0.f, 0.f, 0.f};
        const int row = nb * 16 + l15;
        const int r7  = row & 7;
#pragma unroll
        for (int ds = 0; ds < 4; ++ds) {
          const bf16x8 kf = *(const bf16x8*)&Ks[cur][row * 128 + (((ds * 4 + lq) ^ r7) * 8)];
          s0[nb] = __builtin_amdgcn_mfma_f32_16x16x32_bf16(kf, qf0[ds], s0[nb], 0, 0, 0);
          s1[nb] = __builtin_amdgcn_mfma_f32_16x16x32_bf16(kf, qf1[ds], s1[nb], 0, 0, 0);
        }
      }

      // ---- p = exp2(s) raw (no max); mask only last two tiles ----
      const bool dia = (kt >= nkt - 2);
#pragma unroll
      for (int nb = 0; nb < 4; ++nb) {
        const int kvb = kt * 64 + nb * 16 + lq * 4;
        float p0, p1, p2, p3;
        if (dia) {
          p0 = (kvb + 0 <= qa0) ? fast_exp2(s0[nb][0]) : 0.f;
          p1 = (kvb + 1 <= qa0) ? fast_exp2(s0[nb][1]) : 0.f;
          p2 = (kvb + 2 <= qa0) ? fast_exp2(s0[nb][2]) : 0.f;
          p3 = (kvb + 3 <= qa0) ? fast_exp2(s0[nb][3]) : 0.f;
        } else {
          p0 = fast_exp2(s0[nb][0]);
          p1 = fast_exp2(s0[nb][1]);
          p2 = fast_exp2(s0[nb][2]);
          p3 = fast_exp2(s0[nb][3]);
        }
        l0 += (p0 + p1) + (p2 + p3);
        *(bf16x4*)(Psw + l15 * PSTR + nb * 16 + lq * 4) =
            bf16x4{(__bf16)p0, (__bf16)p1, (__bf16)p2, (__bf16)p3};

        if (dia) {
          p0 = (kvb + 0 <= qa1) ? fast_exp2(s1[nb][0]) : 0.f;
          p1 = (kvb + 1 <= qa1) ? fast_exp2(s1[nb][1]) : 0.f;
          p2 = (kvb + 2 <= qa1) ? fast_exp2(s1[nb][2]) : 0.f;
          p3 = (kvb + 3 <= qa1) ? fast_exp2(s1[nb][3]) : 0.f;
        } else {
          p0 = fast_exp2(s1[nb][0]);
          p1 = fast_exp2(s1[nb][1]);
          p2 = fast_exp2(s1[nb][2]);
          p3 = fast_exp2(s1[nb][3]);
        }
        l1 += (p0 + p1) + (p2 + p3);
        *(bf16x4*)(Psw + (16 + l15) * PSTR + nb * 16 + lq * 4) =
            bf16x4{(__bf16)p0, (__bf16)p1, (__bf16)p2, (__bf16)p3};
      }

      // wait ONLY LDS (keep K/V prefetch in flight)
      asm volatile("s_waitcnt lgkmcnt(0)" ::: "memory");

      // ---- O^T += V^T P^T. vf read ONCE, used for both f ----
#pragma unroll
      for (int ks = 0; ks < 2; ++ks) {
        const bf16x8 pf0 = *(const bf16x8*)(Psw + l15 * PSTR + ks * 32 + lq * 8);
        const bf16x8 pf1 = *(const bf16x8*)(Psw + (16 + l15) * PSTR + ks * 32 + lq * 8);
#pragma unroll
        for (int nb = 0; nb < 8; ++nb) {
          const int row = nb * 16 + l15;
          const bf16x8 vf = *(const bf16x8*)&Vs[cur][row * 64 + (((ks * 4 + lq) ^ (row & 7)) * 8)];
          o0[nb] = __builtin_amdgcn_mfma_f32_16x16x32_bf16(vf, pf0, o0[nb], 0, 0, 0);
          o1[nb] = __builtin_amdgcn_mfma_f32_16x16x32_bf16(vf, pf1, o1[nb], 0, 0, 0);
        }
      }
    }

    // ---- epilogue: reduce l over lq-group (lanes l15+16*lq), store ----
    float lt0 = l0, lt1 = l1;
    lt0 += __shfl_xor(lt0, 16);
    lt0 += __shfl_xor(lt0, 32);
    lt1 += __shfl_xor(lt1, 16);
    lt1 += __shfl_xor(lt1, 32);
    const float inv0 = 1.f / lt0;
    const float inv1 = 1.f / lt1;
    bf16_t* yp0 = Y + ((size_t)(b * T_SEQ + qa0) * NH + h) * HD + lq * 4;
    bf16_t* yp1 = Y + ((size_t)(b * T_SEQ + qa1) * NH + h) * HD + lq * 4;
#pragma unroll
    for (int nb = 0; nb < 8; ++nb) {
      *(bf16x4*)(yp0 + nb * 16) = bf16x4{(__bf16)(o0[nb][0] * inv0), (__bf16)(o0[nb][1] * inv0),
                                         (__bf16)(o0[nb][2] * inv0), (__bf16)(o0[nb][3] * inv0)};
      *(bf16x4*)(yp1 + nb * 16) = bf16x4{(__bf16)(o1[nb][0] * inv1), (__bf16)(o1[nb][1] * inv1),
                                         (__bf16)(o1[nb][2] * inv1), (__bf16)(o1[nb][3] * inv1)};
    }
  }
}

// =====================================================================
// launch
// =====================================================================
extern "C" void kernel_launch(void* const* d_in, const int* in_sizes, int n_in,
                              void* d_out, int out_size, void* d_ws, size_t ws_size,
                              hipStream_t stream) {
  const float* x  = (const float*)d_in[0];
  const float* wq = (const float*)d_in[1];
  const float* wk = (const float*)d_in[2];
  const float* wv = (const float*)d_in[3];
  const float* wo = (const float*)d_in[4];
  float* out = (float*)d_out;

  const size_t n_x  = (size_t)MROWS * EMB;
  const size_t n_wq = (size_t)EMB * EMB;
  const size_t n_wk = (size_t)KVDIM * EMB;

  bf16_t* xb  = (bf16_t*)d_ws;
  bf16_t* wqb = xb  + n_x;
  bf16_t* wkb = wqb + n_wq;
  bf16_t* wvb = wkb + n_wk;
  bf16_t* wob = wvb + n_wk;
  bf16_t* Qb  = wob + n_wq;                  // 4096*2048
  bf16_t* Kb  = Qb + (size_t)MROWS * EMB;    // 4096*512
  bf16_t* Vtb = Kb + (size_t)MROWS * KVDIM;  // (B*512)*2048 transposed V
  bf16_t* Yb  = Vtb + (size_t)MROWS * KVDIM; // 4096*2048

  dim3 blk(256);

  cvt_all<<<dim3(18432), blk, 0, stream>>>(
      (const float4*)x, (const float4*)wq, (const float4*)wk, (const float4*)wv, (const float4*)wo,
      (bf16x4*)xb, (bf16x4*)wqb, (bf16x4*)wkb, (bf16x4*)wvb, (bf16x4*)wob);

  const float qalpha = 0.08838834764831845f * 1.4426950408889634f;
  gemm_qkv8<<<dim3(192), dim3(512), 0, stream>>>(xb, wqb, wkb, wvb,
                                                 Qb, Kb, Vtb, qalpha);

  attn_fwd<<<dim3(8, NH, BATCH), blk, 0, stream>>>(Qb, Kb, Vtb, Yb);

  gemm_out<<<dim3(EMB / 128, MROWS / 128), blk, 0, stream>>>(Yb, wob, out, MROWS, EMB, EMB);
}

// Round 7
// 301.765 us; speedup vs baseline: 1.0004x; 1.0004x over previous
//
#include <hip/hip_runtime.h>
#include <cstdint>
#include <cstddef>

// ---------- types ----------
typedef __bf16 bf16_t;
typedef __bf16 bf16x8 __attribute__((ext_vector_type(8)));
typedef __bf16 bf16x4 __attribute__((ext_vector_type(4)));
typedef float f32x4 __attribute__((ext_vector_type(4)));

// async global->LDS, 16B per lane. LDS dest must be wave-uniform base + lane*16.
#define GL2LDS16(gptr, lptr)                                                   \
  __builtin_amdgcn_global_load_lds(                                            \
      (__attribute__((address_space(1))) void*)(gptr),                         \
      (__attribute__((address_space(3))) void*)(lptr), 16, 0, 0)

// fast 2^x (hardware transcendental; inputs bounded here)
__device__ __forceinline__ float fast_exp2(float x) {
  float r;
  asm volatile("v_exp_f32 %0, %1" : "=v"(r) : "v"(x));
  return r;
}

// ---------- problem constants ----------
#define BATCH 2
#define T_SEQ 2048
#define NH 16
#define NKV 4
#define HD 128
#define EMB 2048
#define KVDIM (NKV * HD)       // 512
#define MROWS (BATCH * T_SEQ)  // 4096

// =====================================================================
// fused fp32 -> bf16 conversion for all 5 inputs (one dispatch)
// =====================================================================
__global__ void cvt_all(const float4* __restrict__ x,  const float4* __restrict__ wq,
                        const float4* __restrict__ wk, const float4* __restrict__ wv,
                        const float4* __restrict__ wo,
                        bf16x4* __restrict__ xb,  bf16x4* __restrict__ wqb,
                        bf16x4* __restrict__ wkb, bf16x4* __restrict__ wvb,
                        bf16x4* __restrict__ wob) {
  const int blk = blockIdx.x;
  const float4* src;
  bf16x4* dst;
  int base;
  if (blk < 8192)       { src = x;  dst = xb;  base = blk; }
  else if (blk < 12288) { src = wq; dst = wqb; base = blk - 8192; }
  else if (blk < 13312) { src = wk; dst = wkb; base = blk - 12288; }
  else if (blk < 14336) { src = wv; dst = wvb; base = blk - 13312; }
  else                  { src = wo; dst = wob; base = blk - 14336; }
  const int i = base * 256 + threadIdx.x;
  const float4 v = src[i];
  dst[i] = bf16x4{(__bf16)v.x, (__bf16)v.y, (__bf16)v.z, (__bf16)v.w};
}

// =====================================================================
// Fused QKV GEMM — R2-exact 256x256 8-phase schedule (best measured:
// 67.3 µs). 8 waves, wave tile 128x64, BK=64, LDS 128 KiB, 16B-block
// XOR swizzle, counted vmcnt(6) once per K-tile, setprio around MFMA.
// Region liveness: A free after ph3, B free after ph2.
// Stage slots: ph1 -> (t+1).A1 [nxt]; ph2 -> none;
//              ph3 -> (t+2).B0 [cur]; ph4 -> (t+2).A0 + (t+2).B1 [cur].
// N tiles: [0,8) Q | [8,10) K | [10,12) V^T.  Grid: 192 blocks, XCD-swizzled.
// =====================================================================
#define BK8 64
#define NT8 (EMB / BK8)  // 32

__global__ __launch_bounds__(512, 2)
void gemm_qkv8(const bf16_t* __restrict__ A,
               const bf16_t* __restrict__ Wq, const bf16_t* __restrict__ Wk,
               const bf16_t* __restrict__ Wv,
               bf16_t* __restrict__ Qb, bf16_t* __restrict__ Kb,
               bf16_t* __restrict__ Vt, float qalpha)
{
  // rows 0..255: A tile (two 128-row halves), rows 256..511: B tile.
  __shared__ bf16_t lds[2][512 * 64];

  const int tid  = threadIdx.x;
  const int lane = tid & 63;
  const int wv   = tid >> 6;
  const int l15  = lane & 15;
  const int lq   = lane >> 4;

  // XCD-aware bijective swizzle: 192 blocks = 8 XCDs x 24.
  const int bid0 = blockIdx.x;
  const int bid  = (bid0 & 7) * 24 + (bid0 >> 3);
  const int mt = bid / 12, nt = bid % 12;
  const int m0 = mt * 256;

  const bf16_t* Bmat; int ncol0, seg;
  if (nt < 8)       { Bmat = Wq; ncol0 = nt * 256;        seg = 0; }
  else if (nt < 10) { Bmat = Wk; ncol0 = (nt - 8) * 256;  seg = 1; }
  else              { Bmat = Wv; ncol0 = (nt - 10) * 256; seg = 2; }

  const int wm = (wv >> 2) * 128;  // wave M offset (0/128)
  const int wn = (wv & 3) * 64;    // wave N offset (0/64/128/192)

  f32x4 acc[8][4] = {};

  // stage half-tile h of K-tile tsrc into lds[dbuf].
  auto stage = [&](int dbuf, int tsrc, int h) {
    const int k0 = tsrc * BK8;
    const bf16_t* src = (h < 2) ? A : Bmat;
    const int rbase = (h < 2) ? (m0 + h * 128) : (ncol0 + (h - 2) * 128);
    bf16_t* dst = &lds[dbuf][h * 8192];
#pragma unroll
    for (int r = 0; r < 2; ++r) {
      const int c = r * 512 + tid;          // 0..1023, 16B granules
      const int row = c >> 3, p = c & 7;
      const int sb = p ^ (row & 7);
      GL2LDS16(src + (size_t)(rbase + row) * EMB + k0 + sb * 8, dst + c * 8);
    }
  };

  // ---- prologue: tile0 complete + tile1 {B0,A0,B1} in flight ----
  stage(0, 0, 0); stage(0, 0, 1); stage(0, 0, 2); stage(0, 0, 3);
  stage(1, 1, 2); stage(1, 1, 0); stage(1, 1, 3);
  asm volatile("s_waitcnt vmcnt(6)" ::: "memory");  // tile0's 8 loads landed
  __builtin_amdgcn_s_barrier();

  bf16x8 a[4][2], b[4][2];

#pragma unroll 1
  for (int tt = 0; tt < NT8; tt += 2) {
#pragma unroll
    for (int u = 0; u < 2; ++u) {
      const int t   = tt + u;
      const int cur = u;
      const int nxt = u ^ 1;
      const int tn1 = (t + 1 < NT8) ? t + 1 : NT8 - 1;  // clamp src only;
      const int tn2 = (t + 2 < NT8) ? t + 2 : NT8 - 1;  // dest parity stays

      // ------- phase 1: read A[i0-3], B[j0-1]; stage (t+1).A1 [nxt] ------
#pragma unroll
      for (int i = 0; i < 4; ++i) {
        const int row = wm + i * 16 + l15;
#pragma unroll
        for (int ks = 0; ks < 2; ++ks)
          a[i][ks] = *(const bf16x8*)&lds[cur][row * 64 + (((ks * 4 + lq) ^ (row & 7)) * 8)];
      }
#pragma unroll
      for (int j = 0; j < 2; ++j) {
        const int row = 256 + wn + j * 16 + l15;
#pragma unroll
        for (int ks = 0; ks < 2; ++ks)
          b[j][ks] = *(const bf16x8*)&lds[cur][row * 64 + (((ks * 4 + lq) ^ (row & 7)) * 8)];
      }
      stage(nxt, tn1, 1);
      __builtin_amdgcn_s_barrier();
      __builtin_amdgcn_s_setprio(1);
#pragma unroll
      for (int ks = 0; ks < 2; ++ks)
#pragma unroll
        for (int i = 0; i < 4; ++i)
#pragma unroll
          for (int j = 0; j < 2; ++j)
            acc[i][j] = __builtin_amdgcn_mfma_f32_16x16x32_bf16(a[i][ks], b[j][ks], acc[i][j], 0, 0, 0);
      __builtin_amdgcn_s_setprio(0);
      __builtin_amdgcn_s_barrier();

      // ------- phase 2: read B[j2-3]; NO stage (all cur regions live) ----
#pragma unroll
      for (int j = 2; j < 4; ++j) {
        const int row = 256 + wn + j * 16 + l15;
#pragma unroll
        for (int ks = 0; ks < 2; ++ks)
          b[j][ks] = *(const bf16x8*)&lds[cur][row * 64 + (((ks * 4 + lq) ^ (row & 7)) * 8)];
      }
      __builtin_amdgcn_s_barrier();
      __builtin_amdgcn_s_setprio(1);
#pragma unroll
      for (int ks = 0; ks < 2; ++ks)
#pragma unroll
        for (int i = 0; i < 4; ++i)
#pragma unroll
          for (int j = 2; j < 4; ++j)
            acc[i][j] = __builtin_amdgcn_mfma_f32_16x16x32_bf16(a[i][ks], b[j][ks], acc[i][j], 0, 0, 0);
      __builtin_amdgcn_s_setprio(0);
      __builtin_amdgcn_s_barrier();

      // ------- phase 3: read A[i4-7]; stage (t+2).B0 (B free after ph2) --
#pragma unroll
      for (int i = 0; i < 4; ++i) {
        const int row = wm + (4 + i) * 16 + l15;
#pragma unroll
        for (int ks = 0; ks < 2; ++ks)
          a[i][ks] = *(const bf16x8*)&lds[cur][row * 64 + (((ks * 4 + lq) ^ (row & 7)) * 8)];
      }
      stage(cur, tn2, 2);
      __builtin_amdgcn_s_barrier();
      __builtin_amdgcn_s_setprio(1);
#pragma unroll
      for (int ks = 0; ks < 2; ++ks)
#pragma unroll
        for (int i = 0; i < 4; ++i)
#pragma unroll
          for (int j = 2; j < 4; ++j)
            acc[4 + i][j] = __builtin_amdgcn_mfma_f32_16x16x32_bf16(a[i][ks], b[j][ks], acc[4 + i][j], 0, 0, 0);
      __builtin_amdgcn_s_setprio(0);
      __builtin_amdgcn_s_barrier();

      // ------- phase 4: stage (t+2).A0 + (t+2).B1 (A free after ph3) -----
      stage(cur, tn2, 0);
      stage(cur, tn2, 3);
      __builtin_amdgcn_s_barrier();
      __builtin_amdgcn_s_setprio(1);
#pragma unroll
      for (int ks = 0; ks < 2; ++ks)
#pragma unroll
        for (int i = 0; i < 4; ++i)
#pragma unroll
          for (int j = 0; j < 2; ++j)
            acc[4 + i][j] = __builtin_amdgcn_mfma_f32_16x16x32_bf16(a[i][ks], b[j][ks], acc[4 + i][j], 0, 0, 0);
      __builtin_amdgcn_s_setprio(0);
      asm volatile("s_waitcnt vmcnt(6)" ::: "memory");
      __builtin_amdgcn_s_barrier();
    }
  }
  asm volatile("s_waitcnt vmcnt(0)" ::: "memory");  // drain tail dummies

  // ---- epilogue ----
  if (seg == 0) {          // Q: scale + row-major (4096,2048)
#pragma unroll
    for (int i = 0; i < 8; ++i) {
      const int rbase = m0 + wm + i * 16 + lq * 4;
#pragma unroll
      for (int j = 0; j < 4; ++j) {
        const int col = ncol0 + wn + j * 16 + l15;
#pragma unroll
        for (int r = 0; r < 4; ++r)
          Qb[(size_t)(rbase + r) * EMB + col] = (bf16_t)(acc[i][j][r] * qalpha);
      }
    }
  } else if (seg == 1) {   // K: row-major (4096,512)
#pragma unroll
    for (int i = 0; i < 8; ++i) {
      const int rbase = m0 + wm + i * 16 + lq * 4;
#pragma unroll
      for (int j = 0; j < 4; ++j) {
        const int col = ncol0 + wn + j * 16 + l15;
#pragma unroll
        for (int r = 0; r < 4; ++r)
          Kb[(size_t)(rbase + r) * KVDIM + col] = (bf16_t)acc[i][j][r];
      }
    }
  } else {                 // V: transposed, 4 consecutive t per lane
    const int bb = m0 >> 11;
    const int mloc0 = (m0 & 2047) + wm + lq * 4;
#pragma unroll
    for (int i = 0; i < 8; ++i) {
      const int mloc = mloc0 + i * 16;
#pragma unroll
      for (int j = 0; j < 4; ++j) {
        const int d = ncol0 + wn + j * 16 + l15;
        *(bf16x4*)(Vt + (size_t)(bb * KVDIM + d) * T_SEQ + mloc) =
            bf16x4{(__bf16)acc[i][j][0], (__bf16)acc[i][j][1],
                   (__bf16)acc[i][j][2], (__bf16)acc[i][j][3]};
      }
    }
  }
}

// =====================================================================
// GEMM (out-projection): fp32 out.
// =====================================================================
__global__ __launch_bounds__(256, 2)
void gemm_out(const bf16_t* __restrict__ A, const bf16_t* __restrict__ Bm,
              float* __restrict__ C, int M, int N, int K)
{
  __shared__ bf16_t As[128 * 64];
  __shared__ bf16_t Bs[128 * 64];

  const int tid  = threadIdx.x;
  const int lane = tid & 63;
  const int wv   = tid >> 6;
  const int m0 = blockIdx.y * 128;
  const int n0 = blockIdx.x * 128;
  const int wm = (wv >> 1) * 64;
  const int wn = (wv & 1) * 64;
  const int l15 = lane & 15;
  const int lq  = lane >> 4;

  f32x4 acc[4][4] = {};
  const int srow = tid >> 3;
  const int scol = (tid & 7) * 8;

  for (int k0 = 0; k0 < K; k0 += 64) {
#pragma unroll
    for (int r = 0; r < 4; ++r) {
      const int row = r * 32 + srow;
      GL2LDS16(A + (size_t)(m0 + row) * K + k0 + scol, As + row * 64 + scol);
    }
#pragma unroll
    for (int r = 0; r < 4; ++r) {
      const int row = r * 32 + srow;
      GL2LDS16(Bm + (size_t)(n0 + row) * K + k0 + scol, Bs + row * 64 + scol);
    }
    __syncthreads();

#pragma unroll
    for (int ks = 0; ks < 2; ++ks) {
      const int kc = ks * 32 + lq * 8;
      bf16x8 af[4], bf[4];
#pragma unroll
      for (int i = 0; i < 4; ++i)
        af[i] = *(const bf16x8*)(As + (wm + i * 16 + l15) * 64 + kc);
#pragma unroll
      for (int j = 0; j < 4; ++j)
        bf[j] = *(const bf16x8*)(Bs + (wn + j * 16 + l15) * 64 + kc);
#pragma unroll
      for (int i = 0; i < 4; ++i)
#pragma unroll
        for (int j = 0; j < 4; ++j)
          acc[i][j] = __builtin_amdgcn_mfma_f32_16x16x32_bf16(af[i], bf[j], acc[i][j], 0, 0, 0);
    }
    __syncthreads();
  }

#pragma unroll
  for (int i = 0; i < 4; ++i) {
    const int rbase = m0 + wm + i * 16 + lq * 4;
#pragma unroll
    for (int j = 0; j < 4; ++j) {
      const int col = n0 + wn + j * 16 + l15;
#pragma unroll
      for (int r = 0; r < 4; ++r)
        C[(size_t)(rbase + r) * N + col] = acc[i][j][r];
    }
  }
}

// =====================================================================
// Flash attention — 32 q-rows/wave (dual l15-fragment ILP, R6-verified
// math) + SPLIT softmax/PV to shrink Ps 18.4K -> 10K (PSTR=40):
// LDS = Ks 32K + Vs 32K + Ps 10K = 74K -> 2 blocks/CU, 8 waves/CU
// (fixes R6's 1-wave/SIMD occupancy collapse).
// Per kv-tile: QK(kv 0..31) -> exp+write halfA -> QK(kv 32..63)
// [overlaps halfA drain] -> lgkm -> PV(ks=0) -> exp+write halfB into
// SAME cols [per-wave in-order DS: reads before overwrite] -> lgkm ->
// PV(ks=1). K/V fragment reads shared across both q-fragments.
// Grid (16,NH,B) = 512 blocks @2/CU, qt = 15-bx (heavy blocks first;
// causal imbalance evens out via 2x oversubscription).
// Masking: last TWO kv tiles elementwise kvb<=qabs (exact, R6-verified).
// =====================================================================
#define PSTR 40   // 80 B row stride: 16B-aligned, 2-way-bank-free

__global__ __launch_bounds__(256, 2)
void attn_fwd(const bf16_t* __restrict__ Q, const bf16_t* __restrict__ Kg,
              const bf16_t* __restrict__ Vt, bf16_t* __restrict__ Y)
{
  __shared__ bf16_t Ks[2][64 * 128];   // [t 0..63][16B blk], blk = pos ^ (t&7)
  __shared__ bf16_t Vs[2][128 * 64];   // [d 0..127][16B blk], blk = pos ^ (d&7)
  __shared__ bf16_t Ps[4][32 * PSTR];  // per-wave P[q 0..31][kv-half 0..31]

  const int tid  = threadIdx.x;
  const int lane = tid & 63;
  const int wv   = tid >> 6;
  const int l15  = lane & 15;
  const int lq   = lane >> 4;
  const int h  = blockIdx.y;
  const int b  = blockIdx.z;
  const int hkv = h >> 2;
  bf16_t* Psw = Ps[wv];

  auto stage = [&](int kt, int bufsel) {
    const int base_t = b * T_SEQ + kt * 64;
#pragma unroll
    for (int r = 0; r < 4; ++r) {
      const int c = r * 256 + tid;
      const int row = c >> 4, p = c & 15;
      const int sb = p ^ (row & 7);
      GL2LDS16(Kg + (size_t)(base_t + row) * KVDIM + hkv * HD + sb * 8,
               &Ks[bufsel][c * 8]);
    }
#pragma unroll
    for (int r = 0; r < 4; ++r) {
      const int c = r * 256 + tid;
      const int row = c >> 3, p = c & 7;
      const int sb = p ^ (row & 7);
      GL2LDS16(Vt + (size_t)(b * KVDIM + hkv * HD + row) * T_SEQ + kt * 64 + sb * 8,
               &Vs[bufsel][c * 8]);
    }
  };

  const int qt  = 15 - blockIdx.x;       // heavy blocks dispatch first
  const int q0  = qt * 128;
  const int nkt = 2 * qt + 2;            // kv tiles of 64
  const int qa0 = q0 + wv * 32 + l15;    // f=0 q row
  const int qa1 = qa0 + 16;              // f=1 q row

  // Q fragments (B-operand: n=l15=q, k=lq*8+j). Q pre-scaled.
  bf16x8 qf0[4], qf1[4];
  {
    const bf16_t* qp0 = Q + ((size_t)(b * T_SEQ + qa0) * NH + h) * HD + lq * 8;
    const bf16_t* qp1 = Q + ((size_t)(b * T_SEQ + qa1) * NH + h) * HD + lq * 8;
#pragma unroll
    for (int ds = 0; ds < 4; ++ds) {
      qf0[ds] = *(const bf16x8*)(qp0 + ds * 32);
      qf1[ds] = *(const bf16x8*)(qp1 + ds * 32);
    }
  }

  float l0 = 0.f, l1 = 0.f;
  f32x4 o0[8], o1[8];
#pragma unroll
  for (int nb = 0; nb < 8; ++nb) {
    o0[nb] = f32x4{0.f, 0.f, 0.f, 0.f};
    o1[nb] = f32x4{0.f, 0.f, 0.f, 0.f};
  }

  stage(0, 0);

  for (int kt = 0; kt < nkt; ++kt) {
    const int cur = kt & 1;
    __syncthreads();          // stage(kt) complete (barrier drains vmcnt)
    if (kt + 1 < nkt) stage(kt + 1, cur ^ 1);
    const bool dia = (kt >= nkt - 2);

    // ---- QK^T half A (kv 0..31): nb 0,1; kf shared across fragments ----
    f32x4 sA0[2], sA1[2];
#pragma unroll
    for (int nb = 0; nb < 2; ++nb) {
      sA0[nb] = f32x4{0.f, 0.f, 0.f, 0.f};
      sA1[nb] = f32x4{0.f, 0.f, 0.f, 0.f};
      const int row = nb * 16 + l15;
      const int r7  = row & 7;
#pragma unroll
      for (int ds = 0; ds < 4; ++ds) {
        const bf16x8 kf = *(const bf16x8*)&Ks[cur][row * 128 + (((ds * 4 + lq) ^ r7) * 8)];
        sA0[nb] = __builtin_amdgcn_mfma_f32_16x16x32_bf16(kf, qf0[ds], sA0[nb], 0, 0, 0);
        sA1[nb] = __builtin_amdgcn_mfma_f32_16x16x32_bf16(kf, qf1[ds], sA1[nb], 0, 0, 0);
      }
    }
    // exp + write half A (cols 0..31)
#pragma unroll
    for (int nb = 0; nb < 2; ++nb) {
      const int kvb = kt * 64 + nb * 16 + lq * 4;
      float p0, p1, p2, p3;
      if (dia) {
        p0 = (kvb + 0 <= qa0) ? fast_exp2(sA0[nb][0]) : 0.f;
        p1 = (kvb + 1 <= qa0) ? fast_exp2(sA0[nb][1]) : 0.f;
        p2 = (kvb + 2 <= qa0) ? fast_exp2(sA0[nb][2]) : 0.f;
        p3 = (kvb + 3 <= qa0) ? fast_exp2(sA0[nb][3]) : 0.f;
      } else {
        p0 = fast_exp2(sA0[nb][0]); p1 = fast_exp2(sA0[nb][1]);
        p2 = fast_exp2(sA0[nb][2]); p3 = fast_exp2(sA0[nb][3]);
      }
      l0 += (p0 + p1) + (p2 + p3);
      *(bf16x4*)(Psw + l15 * PSTR + nb * 16 + lq * 4) =
          bf16x4{(__bf16)p0, (__bf16)p1, (__bf16)p2, (__bf16)p3};

      if (dia) {
        p0 = (kvb + 0 <= qa1) ? fast_exp2(sA1[nb][0]) : 0.f;
        p1 = (kvb + 1 <= qa1) ? fast_exp2(sA1[nb][1]) : 0.f;
        p2 = (kvb + 2 <= qa1) ? fast_exp2(sA1[nb][2]) : 0.f;
        p3 = (kvb + 3 <= qa1) ? fast_exp2(sA1[nb][3]) : 0.f;
      } else {
        p0 = fast_exp2(sA1[nb][0]); p1 = fast_exp2(sA1[nb][1]);
        p2 = fast_exp2(sA1[nb][2]); p3 = fast_exp2(sA1[nb][3]);
      }
      l1 += (p0 + p1) + (p2 + p3);
      *(bf16x4*)(Psw + (16 + l15) * PSTR + nb * 16 + lq * 4) =
          bf16x4{(__bf16)p0, (__bf16)p1, (__bf16)p2, (__bf16)p3};
    }

    // ---- QK^T half B (kv 32..63): overlaps half-A write drain ----
    f32x4 sB0[2], sB1[2];
#pragma unroll
    for (int nb = 0; nb < 2; ++nb) {
      sB0[nb] = f32x4{0.f, 0.f, 0.f, 0.f};
      sB1[nb] = f32x4{0.f, 0.f, 0.f, 0.f};
      const int row = (nb + 2) * 16 + l15;
      const int r7  = row & 7;
#pragma unroll
      for (int ds = 0; ds < 4; ++ds) {
        const bf16x8 kf = *(const bf16x8*)&Ks[cur][row * 128 + (((ds * 4 + lq) ^ r7) * 8)];
        sB0[nb] = __builtin_amdgcn_mfma_f32_16x16x32_bf16(kf, qf0[ds], sB0[nb], 0, 0, 0);
        sB1[nb] = __builtin_amdgcn_mfma_f32_16x16x32_bf16(kf, qf1[ds], sB1[nb], 0, 0, 0);
      }
    }

    // ---- PV ks=0 (half-A P): vf shared across fragments ----
    asm volatile("s_waitcnt lgkmcnt(0)" ::: "memory");
    {
      const bf16x8 pf0 = *(const bf16x8*)(Psw + l15 * PSTR + lq * 8);
      const bf16x8 pf1 = *(const bf16x8*)(Psw + (16 + l15) * PSTR + lq * 8);
#pragma unroll
      for (int nb = 0; nb < 8; ++nb) {
        const int row = nb * 16 + l15;
        const bf16x8 vf = *(const bf16x8*)&Vs[cur][row * 64 + ((lq ^ (row & 7)) * 8)];
        o0[nb] = __builtin_amdgcn_mfma_f32_16x16x32_bf16(vf, pf0, o0[nb], 0, 0, 0);
        o1[nb] = __builtin_amdgcn_mfma_f32_16x16x32_bf16(vf, pf1, o1[nb], 0, 0, 0);
      }
    }

    // ---- exp + write half B into SAME cols (kv 32..63 -> cols 0..31) ----
    // (per-wave in-order DS: PV0's reads above complete before overwrite)
#pragma unroll
    for (int nb = 0; nb < 2; ++nb) {
      const int kvb = kt * 64 + (nb + 2) * 16 + lq * 4;
      float p0, p1, p2, p3;
      if (dia) {
        p0 = (kvb + 0 <= qa0) ? fast_exp2(sB0[nb][0]) : 0.f;
        p1 = (kvb + 1 <= qa0) ? fast_exp2(sB0[nb][1]) : 0.f;
        p2 = (kvb + 2 <= qa0) ? fast_exp2(sB0[nb][2]) : 0.f;
        p3 = (kvb + 3 <= qa0) ? fast_exp2(sB0[nb][3]) : 0.f;
      } else {
        p0 = fast_exp2(sB0[nb][0]); p1 = fast_exp2(sB0[nb][1]);
        p2 = fast_exp2(sB0[nb][2]); p3 = fast_exp2(sB0[nb][3]);
      }
      l0 += (p0 + p1) + (p2 + p3);
      *(bf16x4*)(Psw + l15 * PSTR + nb * 16 + lq * 4) =
          bf16x4{(__bf16)p0, (__bf16)p1, (__bf16)p2, (__bf16)p3};

      if (dia) {
        p0 = (kvb + 0 <= qa1) ? fast_exp2(sB1[nb][0]) : 0.f;
        p1 = (kvb + 1 <= qa1) ? fast_exp2(sB1[nb][1]) : 0.f;
        p2 = (kvb + 2 <= qa1) ? fast_exp2(sB1[nb][2]) : 0.f;
        p3 = (kvb + 3 <= qa1) ? fast_exp2(sB1[nb][3]) : 0.f;
      } else {
        p0 = fast_exp2(sB1[nb][0]); p1 = fast_exp2(sB1[nb][1]);
        p2 = fast_exp2(sB1[nb][2]); p3 = fast_exp2(sB1[nb][3]);
      }
      l1 += (p0 + p1) + (p2 + p3);
      *(bf16x4*)(Psw + (16 + l15) * PSTR + nb * 16 + lq * 4) =
          bf16x4{(__bf16)p0, (__bf16)p1, (__bf16)p2, (__bf16)p3};
    }

    // ---- PV ks=1 (half-B P) ----
    asm volatile("s_waitcnt lgkmcnt(0)" ::: "memory");
    {
      const bf16x8 pf0 = *(const bf16x8*)(Psw + l15 * PSTR + lq * 8);
      const bf16x8 pf1 = *(const bf16x8*)(Psw + (16 + l15) * PSTR + lq * 8);
#pragma unroll
      for (int nb = 0; nb < 8; ++nb) {
        const int row = nb * 16 + l15;
        const bf16x8 vf = *(const bf16x8*)&Vs[cur][row * 64 + ((((4 + lq)) ^ (row & 7)) * 8)];
        o0[nb] = __builtin_amdgcn_mfma_f32_16x16x32_bf16(vf, pf0, o0[nb], 0, 0, 0);
        o1[nb] = __builtin_amdgcn_mfma_f32_16x16x32_bf16(vf, pf1, o1[nb], 0, 0, 0);
      }
    }
  }

  // ---- epilogue: reduce l over lq-group (lanes l15+16*lq), store ----
  float lt0 = l0, lt1 = l1;
  lt0 += __shfl_xor(lt0, 16);
  lt0 += __shfl_xor(lt0, 32);
  lt1 += __shfl_xor(lt1, 16);
  lt1 += __shfl_xor(lt1, 32);
  const float inv0 = 1.f / lt0;
  const float inv1 = 1.f / lt1;
  bf16_t* yp0 = Y + ((size_t)(b * T_SEQ + qa0) * NH + h) * HD + lq * 4;
  bf16_t* yp1 = Y + ((size_t)(b * T_SEQ + qa1) * NH + h) * HD + lq * 4;
#pragma unroll
  for (int nb = 0; nb < 8; ++nb) {
    *(bf16x4*)(yp0 + nb * 16) = bf16x4{(__bf16)(o0[nb][0] * inv0), (__bf16)(o0[nb][1] * inv0),
                                       (__bf16)(o0[nb][2] * inv0), (__bf16)(o0[nb][3] * inv0)};
    *(bf16x4*)(yp1 + nb * 16) = bf16x4{(__bf16)(o1[nb][0] * inv1), (__bf16)(o1[nb][1] * inv1),
                                       (__bf16)(o1[nb][2] * inv1), (__bf16)(o1[nb][3] * inv1)};
  }
}

// =====================================================================
// launch
// =====================================================================
extern "C" void kernel_launch(void* const* d_in, const int* in_sizes, int n_in,
                              void* d_out, int out_size, void* d_ws, size_t ws_size,
                              hipStream_t stream) {
  const float* x  = (const float*)d_in[0];
  const float* wq = (const float*)d_in[1];
  const float* wk = (const float*)d_in[2];
  const float* wv = (const float*)d_in[3];
  const float* wo = (const float*)d_in[4];
  float* out = (float*)d_out;

  const size_t n_x  = (size_t)MROWS * EMB;
  const size_t n_wq = (size_t)EMB * EMB;
  const size_t n_wk = (size_t)KVDIM * EMB;

  bf16_t* xb  = (bf16_t*)d_ws;
  bf16_t* wqb = xb  + n_x;
  bf16_t* wkb = wqb + n_wq;
  bf16_t* wvb = wkb + n_wk;
  bf16_t* wob = wvb + n_wk;
  bf16_t* Qb  = wob + n_wq;                  // 4096*2048
  bf16_t* Kb  = Qb + (size_t)MROWS * EMB;    // 4096*512
  bf16_t* Vtb = Kb + (size_t)MROWS * KVDIM;  // (B*512)*2048 transposed V
  bf16_t* Yb  = Vtb + (size_t)MROWS * KVDIM; // 4096*2048

  dim3 blk(256);

  cvt_all<<<dim3(18432), blk, 0, stream>>>(
      (const float4*)x, (const float4*)wq, (const float4*)wk, (const float4*)wv, (const float4*)wo,
      (bf16x4*)xb, (bf16x4*)wqb, (bf16x4*)wkb, (bf16x4*)wvb, (bf16x4*)wob);

  const float qalpha = 0.08838834764831845f * 1.4426950408889634f;
  gemm_qkv8<<<dim3(192), dim3(512), 0, stream>>>(xb, wqb, wkb, wvb,
                                                 Qb, Kb, Vtb, qalpha);

  attn_fwd<<<dim3(16, NH, BATCH), blk, 0, stream>>>(Qb, Kb, Vtb, Yb);

  gemm_out<<<dim3(EMB / 128, MROWS / 128), blk, 0, stream>>>(Yb, wob, out, MROWS, EMB, EMB);
}